// Round 2
// baseline (792.727 us; speedup 1.0000x reference)
//
#include <hip/hip_runtime.h>

// Problem constants (match reference)
#define NUM_C 37
#define LOG_INV_BETA 0.010050336f
#define LOG_BETA    (-0.010050336f)
#define FLT_MAX_SAT 3.402823466e+38f

#define NBLK 1024                 // 256-thread blocks; 4 blocks/CU (LDS-capped)
#define TILE 256                  // samples per tile (= block size)
#define TILE_DW (TILE * NUM_C)    // 9472 dwords per tile
#define NSLOT 32                  // spread copies for per-class global accumulators
#define SLOT_PITCH 40             // floats per slot copy (37 padded)
// ws float layout:
//   [64 .. 64+32*40)            counts slots
//   [1344 .. 1344+32*40)        P slots
#define WS_CNT 64
#define WS_P   (WS_CNT + NSLOT * SLOT_PITCH)      // 1344
#define WS_TOTAL (WS_P + NSLOT * SLOT_PITCH)      // 2624 floats

// Coalesced staging loads are 16B-aligned: tile base = 37888 B multiple,
// chunk = 4096 B multiple, thread offset = 16 B multiple.
typedef float vf4 __attribute__((ext_vector_type(4)));

// Bit-level finite scrub (integer compare -- survives -ffinite-math-only)
__device__ __forceinline__ float finite_scrub(float v, float sat) {
    unsigned u = __float_as_uint(v);
    if ((u & 0x7f800000u) == 0x7f800000u) return sat;
    return v;
}

// Structure per tile (256 samples, grid-stride over tiles):
//   1. ds_write previously-loaded registers (37 dwords/thread, linear layout)
//   2. __syncthreads
//   3. issue next tile's coalesced global loads into registers (T14: drains
//      under this tile's compute)
//   4. compute: thread k reads LDS row k (dword stride 37 == 5 mod 32 ->
//      2-way bank aliasing, free), single-pass softmax, LDS atomics
//   5. __syncthreads, swap
// Global reads: 9 x dwordx4 + 1 dword per thread, wave-contiguous 1KB per
// instruction -- full TA coalescing, unlike the per-lane-row version.
__global__ __launch_bounds__(256) void fused_main(const float* __restrict__ logits,
                                                  const int* __restrict__ target,
                                                  float* __restrict__ ws,
                                                  int n) {
    __shared__ float tileb[TILE_DW];   // 37888 B
    __shared__ float hP[NUM_C];
    __shared__ unsigned hC[NUM_C];

    const int tid = threadIdx.x;
    if (tid < NUM_C) { hP[tid] = 0.0f; hC[tid] = 0u; }
    __syncthreads();

    const int ntiles = (n + TILE - 1) >> 8;
    float r[NUM_C + 3];   // staged registers (36 via vec4 + 1 scalar)
    int t = 0;

    // prologue: load first tile into registers
    int tile = blockIdx.x;
    if (tile < ntiles) {
        const float* p = logits + (long long)tile * TILE_DW;
        bool full = (((long long)tile + 1) << 8) <= (long long)n;
        if (full) {
#pragma unroll
            for (int c = 0; c < 9; ++c) {
                vf4 v = *(const vf4*)(p + c * 1024 + tid * 4);
                r[4 * c] = v.x; r[4 * c + 1] = v.y; r[4 * c + 2] = v.z; r[4 * c + 3] = v.w;
            }
            r[36] = p[9216 + tid];
        } else {
            int limit = (int)((long long)n - ((long long)tile << 8)) * NUM_C;
#pragma unroll
            for (int c = 0; c < 9; ++c) {
#pragma unroll
                for (int q = 0; q < 4; ++q) {
                    int bi = c * 1024 + tid * 4 + q;
                    r[4 * c + q] = (bi < limit) ? p[bi] : 0.0f;
                }
            }
            int bi = 9216 + tid;
            r[36] = (bi < limit) ? p[bi] : 0.0f;
        }
        long long sb = ((long long)tile << 8) + tid;
        t = (sb < n) ? target[sb] : 0;
        if ((unsigned)t >= NUM_C) t = 0;
    }

    while (tile < ntiles) {
        // ---- 1. registers -> LDS (linear copy of the tile) ----
#pragma unroll
        for (int c = 0; c < 9; ++c) {
            tileb[c * 1024 + tid * 4 + 0] = r[4 * c + 0];
            tileb[c * 1024 + tid * 4 + 1] = r[4 * c + 1];
            tileb[c * 1024 + tid * 4 + 2] = r[4 * c + 2];
            tileb[c * 1024 + tid * 4 + 3] = r[4 * c + 3];
        }
        tileb[9216 + tid] = r[36];
        const int tc = t;
        const int rem = (int)((((long long)n - ((long long)tile << 8)) < TILE)
                                  ? ((long long)n - ((long long)tile << 8)) : TILE);
        __syncthreads();

        // ---- 2. issue next tile's loads (drain under compute) ----
        const int next = tile + gridDim.x;
        if (next < ntiles) {
            const float* p = logits + (long long)next * TILE_DW;
            bool full = (((long long)next + 1) << 8) <= (long long)n;
            if (full) {
#pragma unroll
                for (int c = 0; c < 9; ++c) {
                    vf4 v = *(const vf4*)(p + c * 1024 + tid * 4);
                    r[4 * c] = v.x; r[4 * c + 1] = v.y; r[4 * c + 2] = v.z; r[4 * c + 3] = v.w;
                }
                r[36] = p[9216 + tid];
            } else {
                int limit = (int)((long long)n - ((long long)next << 8)) * NUM_C;
#pragma unroll
                for (int c = 0; c < 9; ++c) {
#pragma unroll
                    for (int q = 0; q < 4; ++q) {
                        int bi = c * 1024 + tid * 4 + q;
                        r[4 * c + q] = (bi < limit) ? p[bi] : 0.0f;
                    }
                }
                int bi = 9216 + tid;
                r[36] = (bi < limit) ? p[bi] : 0.0f;
            }
            long long sb = ((long long)next << 8) + tid;
            t = (sb < n) ? target[sb] : 0;
            if ((unsigned)t >= NUM_C) t = 0;
        }

        // ---- 3. compute current tile from LDS ----
        if (tid < rem) {
            const float* row = &tileb[tid * NUM_C];
            float s0 = 0.0f, s1 = 0.0f, s2 = 0.0f, s3 = 0.0f;
#pragma unroll
            for (int j = 0; j < 36; j += 4) {
                s0 += __expf(row[j]);
                s1 += __expf(row[j + 1]);
                s2 += __expf(row[j + 2]);
                s3 += __expf(row[j + 3]);
            }
            float sum = ((s0 + s1) + (s2 + s3)) + __expf(row[36]);
            float xt = row[tc];
            float ce = __logf(sum) - xt;               // -log_softmax at target
            float pt = __expf(-ce);
            float om = 1.0f - pt;
            float term = fminf(fmaxf(om * om * ce, 0.0f), 1e30f);  // finite, unweighted
            atomicAdd(&hP[tc], term);                  // LDS fp atomic
            atomicAdd(&hC[tc], 1u);
        }

        __syncthreads();   // LDS reusable for next tile
        tile = next;
    }

    if (tid < NUM_C) {
        int slot = blockIdx.x & (NSLOT - 1);
        atomicAdd(&ws[WS_CNT + slot * SLOT_PITCH + tid], (float)hC[tid]);
        atomicAdd(&ws[WS_P   + slot * SLOT_PITCH + tid], hP[tid]);
    }
}

__global__ void finalize_kernel(const float* __restrict__ ws, float* __restrict__ out, int n) {
    int c = threadIdx.x;  // one wave
    float cnt = 0.0f, P = 0.0f;
    if (c < NUM_C) {
#pragma unroll
        for (int sidx = 0; sidx < NSLOT; ++sidx) {
            cnt += ws[WS_CNT + sidx * SLOT_PITCH + c];
            P   += ws[WS_P   + sidx * SLOT_PITCH + c];
        }
    }
    // E = max_c cnt_c * log(1/beta)
    float e = (c < NUM_C) ? cnt * LOG_INV_BETA : 0.0f;
    float E = e;
#pragma unroll
    for (int off = 32; off > 0; off >>= 1) E = fmaxf(E, __shfl_xor(E, off, 64));
    // scaled weighted focal sum: S = sum_c P_c * exp(e_c - E)  (finite, each factor <= 1)
    float term = (c < NUM_C) ? P * __expf(fminf(e - E, 0.0f)) : 0.0f;
    float S = term;
#pragma unroll
    for (int off = 32; off > 0; off >>= 1) S += __shfl_xor(S, off, 64);
    // total and class-weight mean: mean_c beta^(cnt_c/total)
    float total = cnt;
#pragma unroll
    for (int off = 32; off > 0; off >>= 1) total += __shfl_xor(total, off, 64);
    total = fmaxf(total, 1.0f);
    float cw = (c < NUM_C) ? __expf((cnt / total) * LOG_BETA) : 0.0f;
    float s = cw;
#pragma unroll
    for (int off = 32; off > 0; off >>= 1) s += __shfl_xor(s, off, 64);
    if (c == 0) {
        float Sf = finite_scrub(S, 1e30f);
        float Ef = fminf(fmaxf(finite_scrub(E, 1e6f), 0.0f), 1e6f);
        // result = exp(E) * (S/n) * (s/NUM_C), in log space, finite-saturated
        float log_result = Ef + __logf(fmaxf(Sf, 1e-38f) / (float)n)
                              + __logf(fmaxf(s, 1e-38f) / (float)NUM_C);
        float v = __expf(fminf(log_result, 88.0f));   // expf(88)=1.65e38 < FLT_MAX
        if (log_result < -103.0f) v = 0.0f;
        v = finite_scrub(v, FLT_MAX_SAT);             // never store inf/nan
        v = fminf(fmaxf(v, 0.0f), FLT_MAX_SAT);
        out[0] = v;
    }
}

extern "C" void kernel_launch(void* const* d_in, const int* in_sizes, int n_in,
                              void* d_out, int out_size, void* d_ws, size_t ws_size,
                              hipStream_t stream) {
    const float* logits = (const float*)d_in[0];
    const int* target   = (const int*)d_in[1];
    float* out          = (float*)d_out;
    float* ws           = (float*)d_ws;
    int n = in_sizes[1];

    hipMemsetAsync(d_ws, 0, WS_TOTAL * sizeof(float), stream);

    int ntiles = (n + TILE - 1) >> 8;
    int nblocks = ntiles < NBLK ? ntiles : NBLK;
    if (nblocks < 1) nblocks = 1;
    fused_main<<<nblocks, 256, 0, stream>>>(logits, target, ws, n);

    finalize_kernel<<<1, 64, 0, stream>>>(ws, out, n);
}